// Round 6
// baseline (2581.795 us; speedup 1.0000x reference)
//
#include <hip/hip_runtime.h>

// Submanifold sparse conv block, fixed problem size:
// n = 400000 voxels, C = 64, spatial dims B=2, T=21, H=400, W=400.
// lin[i] = ((b*21+t)*400+y)*400+x, sorted ascending by construction.
//
// Round-6: proven VALU math (R1/R2 lineage), restructured for the two
// counter-diagnosed costs: (1) all 27 neighbor-map lookups batched into LDS
// per block (R1 exposed ~27 serial L2/L3 latencies per wave); (2) 4 voxels
// per wave share every weight load (lane = cout, 4 independent accumulators)
// -> W L2 traffic /4 and 4-way FMA ILP. All fp32; W pre-transposed to
// [k][co][ci] for contiguous float4 rows; feature loads are wave-uniform
// (readfirstlane'd SGPR base -> broadcast). MFMA arc abandoned after two
// structural-failure rounds (bug isolated to undocumented A/B input
// fragment mapping; not resolvable headlessly).

#define SBB_T 21
#define SBB_H 400
#define SBB_W 400
#define SBB_TOTAL (2 * SBB_T * SBB_H * SBB_W)   /* 6,720,000 grid sites */
#define SBB_N 400000

__device__ __forceinline__ unsigned short sbb_f2b(float f) {  // RNE
    unsigned u = __float_as_uint(f);
    unsigned r = u + 0x7fffu + ((u >> 16) & 1u);
    return (unsigned short)(r >> 16);
}

__global__ void sbb_lin_kernel(const int* idxs, int* lin, int n) {
    int i = blockIdx.x * 256 + threadIdx.x;
    if (i < n) {
        int b = idxs[4 * i];
        int t = idxs[4 * i + 1];
        int y = idxs[4 * i + 2];
        int x = idxs[4 * i + 3];
        lin[i] = ((b * 21 + t) * 400 + y) * 400 + x;
    }
}

__global__ void sbb_map_init(int* map) {
    int i = blockIdx.x * 256 + threadIdx.x;
    if (i < SBB_TOTAL) map[i] = -1;
}

__global__ void sbb_map_set2(const int* __restrict__ idxs, int* __restrict__ map, int n) {
    int i = blockIdx.x * 256 + threadIdx.x;
    if (i < n) {
        int4 q = ((const int4*)idxs)[i];
        int li = ((q.x * 21 + q.y) * 400 + q.z) * 400 + q.w;
        map[li] = i;
    }
}

__global__ void sbb_map_set(const int* lin, int* map, int n) {
    int i = blockIdx.x * 256 + threadIdx.x;
    if (i < n) map[lin[i]] = i;
}

// w[k][ci][co] fp32 -> wt[k][co][ci] fp32 (unpadded; global reads, not LDS).
__global__ void sbb_wt2(const float* __restrict__ w, float* __restrict__ wt) {
    int k = blockIdx.x;
    const float* ws = w + (size_t)k * 4096;
    float* wd = wt + (size_t)k * 4096;
    for (int e = threadIdx.x; e < 4096; e += 256) {
        int ci = e >> 6;
        int co = e & 63;
        wd[co * 64 + ci] = ws[e];
    }
}

__global__ void sbb_fill_kernel(float* p, int nel, float val) {
    int i = blockIdx.x * 256 + threadIdx.x;
    if (i < nel) p[i] = val;
}

// ---- 4-voxels-per-wave VALU conv + LN (+residual) + ReLU, fp32 ----
// Block = 256 thr = 4 waves, 16 voxels/block. grid = n/16 (exact).
// lane = cout; each wave owns voxels [wid*4, wid*4+4); W loads shared
// across the 4 voxels; 4 independent accumulator chains.
template<int USE_RES>
__global__ __launch_bounds__(256)
void sbb_conv4(const float* __restrict__ A,        // [n][64] fp32
               const float* __restrict__ wt,       // [27][64][64] fp32 [k][co][ci]
               const float* __restrict__ gamma,
               const float* __restrict__ beta,
               const float* __restrict__ residual, // [n][64] fp32 (iff USE_RES)
               float* __restrict__ out,            // [n][64] fp32
               const int* __restrict__ idxs,
               const int* __restrict__ map,
               const float* __restrict__ zpage,    // >=64 fp32 zeros
               int n)
{
    __shared__ int s_nbr[27 * 16];
    __shared__ int s_lin[16];
    __shared__ int s_tyx[16];

    int tid = threadIdx.x;
    int lane = tid & 63;
    int wid = tid >> 6;
    int co = lane;
    int vox0 = blockIdx.x * 16;

    if (tid < 16) {
        int v = vox0 + tid;                       // always < n (n % 16 == 0)
        int4 q = *(const int4*)(idxs + 4 * (size_t)v);
        s_tyx[tid] = (q.y << 20) | (q.z << 10) | q.w;
        s_lin[tid] = ((q.x * 21 + q.y) * 400 + q.z) * 400 + q.w;
    }
    __syncthreads();

    // batched neighbor lookups: 27*16 independent map loads, all in flight
    for (int j = tid; j < 27 * 16; j += 256) {
        int k = j >> 4;
        int v = j & 15;
        int dt = k / 9 - 1;
        int rem = k % 9;
        int dy = rem / 3 - 1;
        int dx = rem % 3 - 1;
        int tyx = s_tyx[v];
        int t0 = tyx >> 20, y0 = (tyx >> 10) & 1023, x0 = tyx & 1023;
        int tt = t0 + dt, yy = y0 + dy, xx = x0 + dx;
        bool valid = ((unsigned)tt < 21u) & ((unsigned)yy < 400u)
                   & ((unsigned)xx < 400u);
        int key = s_lin[v] + dt * (SBB_H * SBB_W) + dy * SBB_W + dx;
        int lo = map[valid ? key : 0];
        s_nbr[j] = valid ? lo : -1;
    }
    __syncthreads();

    float acc0 = 0.f, acc1 = 0.f, acc2 = 0.f, acc3 = 0.f;
    int vb = wid * 4;

    for (int k = 0; k < 27; ++k) {
        int nb0 = s_nbr[(k << 4) + vb + 0];
        int nb1 = s_nbr[(k << 4) + vb + 1];
        int nb2 = s_nbr[(k << 4) + vb + 2];
        int nb3 = s_nbr[(k << 4) + vb + 3];
        int mx01 = nb0 > nb1 ? nb0 : nb1;
        int mx23 = nb2 > nb3 ? nb2 : nb3;
        if ((mx01 > mx23 ? mx01 : mx23) < 0) continue;  // wave-uniform skip

        // wave-uniform values -> force SGPR so feature loads broadcast
        nb0 = __builtin_amdgcn_readfirstlane(nb0);
        nb1 = __builtin_amdgcn_readfirstlane(nb1);
        nb2 = __builtin_amdgcn_readfirstlane(nb2);
        nb3 = __builtin_amdgcn_readfirstlane(nb3);
        const float* b0 = (nb0 >= 0) ? A + (size_t)nb0 * 64 : zpage;
        const float* b1 = (nb1 >= 0) ? A + (size_t)nb1 * 64 : zpage;
        const float* b2 = (nb2 >= 0) ? A + (size_t)nb2 * 64 : zpage;
        const float* b3 = (nb3 >= 0) ? A + (size_t)nb3 * 64 : zpage;

        const float* wr = wt + ((size_t)k << 12) + (co << 6);  // lane's cout row

        #pragma unroll
        for (int c4 = 0; c4 < 16; ++c4) {
            float4 w4 = *(const float4*)(wr + c4 * 4);
            float4 f0 = *(const float4*)(b0 + c4 * 4);
            float4 f1 = *(const float4*)(b1 + c4 * 4);
            float4 f2 = *(const float4*)(b2 + c4 * 4);
            float4 f3 = *(const float4*)(b3 + c4 * 4);
            acc0 = fmaf(f0.x, w4.x, acc0);
            acc0 = fmaf(f0.y, w4.y, acc0);
            acc0 = fmaf(f0.z, w4.z, acc0);
            acc0 = fmaf(f0.w, w4.w, acc0);
            acc1 = fmaf(f1.x, w4.x, acc1);
            acc1 = fmaf(f1.y, w4.y, acc1);
            acc1 = fmaf(f1.z, w4.z, acc1);
            acc1 = fmaf(f1.w, w4.w, acc1);
            acc2 = fmaf(f2.x, w4.x, acc2);
            acc2 = fmaf(f2.y, w4.y, acc2);
            acc2 = fmaf(f2.z, w4.z, acc2);
            acc2 = fmaf(f2.w, w4.w, acc2);
            acc3 = fmaf(f3.x, w4.x, acc3);
            acc3 = fmaf(f3.y, w4.y, acc3);
            acc3 = fmaf(f3.z, w4.z, acc3);
            acc3 = fmaf(f3.w, w4.w, acc3);
        }
    }

    // ---- epilogue: per-voxel LN over the 64 lanes (proven R1/R2 pattern) ----
    float g = gamma[co], bv = beta[co];
    #pragma unroll
    for (int v = 0; v < 4; ++v) {
        float a = (v == 0) ? acc0 : (v == 1) ? acc1 : (v == 2) ? acc2 : acc3;
        float s = a, q = a * a;
        #pragma unroll
        for (int msk = 32; msk > 0; msk >>= 1) {
            s += __shfl_xor(s, msk, 64);
            q += __shfl_xor(q, msk, 64);
        }
        float mean = s * 0.015625f;
        float var = q * 0.015625f - mean * mean;
        var = var < 0.f ? 0.f : var;
        float rstd = rsqrtf(var + 1e-5f);
        float y = (a - mean) * rstd * g + bv;
        size_t oi = (size_t)(vox0 + vb + v) * 64 + co;
        if (USE_RES) y += residual[oi];
        if (y < 0.f) y = 0.f;
        out[oi] = y;
    }
}

// ---- round-1 kernel kept verbatim as the proven fallback ----
__global__ void sbb_conv_old(
    const float* featsf, const unsigned short* featsb, const float* w,
    const float* gamma, const float* beta, const float* residual,
    float* outf, unsigned short* outb, const int* lin, const int* idxs,
    const int* map, int n, int use_residual, int feats_bf16, int out_bf16,
    int use_map)
{
    int tid = threadIdx.x;
    int vox = blockIdx.x * 4 + (tid >> 6);
    if (vox >= n) return;
    int co = tid & 63;

    int t0 = idxs[4 * vox + 1];
    int y0 = idxs[4 * vox + 2];
    int x0 = idxs[4 * vox + 3];
    int mylin = lin[vox];

    float acc = 0.0f;
    #pragma unroll
    for (int dt = -1; dt <= 1; ++dt) {
        int tt = t0 + dt;
        if (tt < 0 || tt >= SBB_T) continue;
        #pragma unroll
        for (int dy = -1; dy <= 1; ++dy) {
            int yy = y0 + dy;
            if (yy < 0 || yy >= SBB_H) continue;
            #pragma unroll
            for (int dx = -1; dx <= 1; ++dx) {
                int xx = x0 + dx;
                if (xx < 0 || xx >= SBB_W) continue;
                int key = mylin + dt * (SBB_H * SBB_W) + dy * SBB_W + dx;
                int lo;
                if (use_map) {
                    lo = map[key];
                } else {
                    int l = 0, h = n;
                    while (l < h) {
                        int mm = (l + h) >> 1;
                        if (lin[mm] < key) l = mm + 1; else h = mm;
                    }
                    lo = (l < n && lin[l] == key) ? l : -1;
                }
                if (lo < 0) continue;
                int kk = (dt + 1) * 9 + (dy + 1) * 3 + (dx + 1);
                const float* wr = w + kk * 4096 + co;
                if (feats_bf16) {
                    const unsigned short* fr = featsb + (size_t)lo * 64;
                    #pragma unroll 4
                    for (int c4 = 0; c4 < 16; ++c4) {
                        ushort4 fv = *(const ushort4*)(fr + c4 * 4);
                        const float* wp = wr + c4 * 256;
                        acc += __uint_as_float(((unsigned)fv.x) << 16) * wp[0];
                        acc += __uint_as_float(((unsigned)fv.y) << 16) * wp[64];
                        acc += __uint_as_float(((unsigned)fv.z) << 16) * wp[128];
                        acc += __uint_as_float(((unsigned)fv.w) << 16) * wp[192];
                    }
                } else {
                    const float4* fr = (const float4*)(featsf + (size_t)lo * 64);
                    #pragma unroll 4
                    for (int c4 = 0; c4 < 16; ++c4) {
                        float4 fv = fr[c4];
                        const float* wp = wr + c4 * 256;
                        acc += fv.x * wp[0];
                        acc += fv.y * wp[64];
                        acc += fv.z * wp[128];
                        acc += fv.w * wp[192];
                    }
                }
            }
        }
    }

    float s = acc, q = acc * acc;
    #pragma unroll
    for (int mm = 32; mm > 0; mm >>= 1) {
        s += __shfl_xor(s, mm, 64);
        q += __shfl_xor(q, mm, 64);
    }
    float mean = s * 0.015625f;
    float var = q * 0.015625f - mean * mean;
    if (var < 0.0f) var = 0.0f;
    float rstd = rsqrtf(var + 1e-5f);

    float yv = (acc - mean) * rstd * gamma[co] + beta[co];
    int oi = vox * 64 + co;
    if (use_residual) yv += residual[oi];
    if (yv < 0.0f) yv = 0.0f;
    if (out_bf16) {
        outb[oi] = sbb_f2b(yv);
    } else {
        outf[oi] = yv;
    }
}

extern "C" void kernel_launch(void* const* d_in, const int* in_sizes, int n_in,
                              void* d_out, int out_size, void* d_ws, size_t ws_size,
                              hipStream_t stream) {
    const float* feats = (const float*)d_in[0];
    const int* idxs = (const int*)d_in[1];
    const float* w1 = (const float*)d_in[2];
    const float* g1 = (const float*)d_in[3];
    const float* b1 = (const float*)d_in[4];
    const float* w2 = (const float*)d_in[5];
    const float* g2 = (const float*)d_in[6];
    const float* b2 = (const float*)d_in[7];
    float* out = (float*)d_out;

    int n = SBB_N;

    size_t map_b  = (size_t)SBB_TOTAL * 4;        // 26.88 MB
    size_t midf_b = (size_t)n * 64 * 4;           // 102.4 MB fp32 mid
    size_t wt_b   = (size_t)27 * 4096 * 4;        // 442368 B per conv (fp32 W^T)
    size_t zb_b   = 512;
    size_t lin_b  = (size_t)n * 4;                // fallback path only
    size_t midb_b = (size_t)n * 64 * 2;           // fallback bf16 mid

    size_t need_new = map_b + midf_b + 2 * wt_b + zb_b;  // 130,165,248 B (proven: ran R5)
    size_t need_old = lin_b + map_b + midb_b;            // 79.7 MB (proven)
    size_t need_min = lin_b + midb_b;                    // 52.8 MB (proven)

    if (ws_size >= need_new) {
        char* p = (char*)d_ws;
        int* map = (int*)p;          p += map_b;
        float* mid = (float*)p;      p += midf_b;
        float* wt1 = (float*)p;      p += wt_b;
        float* wt2 = (float*)p;      p += wt_b;
        float* zb = (float*)p;

        sbb_map_init<<<(SBB_TOTAL + 255) / 256, 256, 0, stream>>>(map);
        sbb_map_set2<<<(n + 255) / 256, 256, 0, stream>>>(idxs, map, n);
        sbb_wt2<<<27, 256, 0, stream>>>(w1, wt1);
        sbb_wt2<<<27, 256, 0, stream>>>(w2, wt2);
        sbb_fill_kernel<<<1, 256, 0, stream>>>(zb, 128, 0.0f);

        int grid_conv = n / 16;                    // 25000 (exact)
        // conv1: feats fp32 in, fp32 mid out, no residual
        sbb_conv4<0><<<grid_conv, 256, 0, stream>>>(
            feats, wt1, g1, b1, feats, mid, idxs, map, zb, n);
        // conv2: fp32 mid in, fp32 out, residual = feats
        sbb_conv4<1><<<grid_conv, 256, 0, stream>>>(
            mid, wt2, g2, b2, feats, out, idxs, map, zb, n);
        return;
    }

    if (ws_size < need_min) {
        sbb_fill_kernel<<<(n * 64 + 255) / 256, 256, 0, stream>>>(out, n * 64, 1000.0f);
        return;
    }

    // fallback: proven round-1 path
    int use_map = (ws_size >= need_old) ? 1 : 0;
    int* lin = (int*)d_ws;
    int* map = nullptr;
    unsigned short* mid;
    if (use_map) {
        map = (int*)((char*)d_ws + lin_b);
        mid = (unsigned short*)((char*)d_ws + lin_b + map_b);
    } else {
        mid = (unsigned short*)((char*)d_ws + lin_b);
    }

    int grid_lin = (n + 255) / 256;
    sbb_lin_kernel<<<grid_lin, 256, 0, stream>>>(idxs, lin, n);
    if (use_map) {
        sbb_map_init<<<(SBB_TOTAL + 255) / 256, 256, 0, stream>>>(map);
        sbb_map_set<<<grid_lin, 256, 0, stream>>>(lin, map, n);
    }

    sbb_conv_old<<<n / 4, 256, 0, stream>>>(
        feats, (const unsigned short*)feats, w1, g1, b1, feats,
        (float*)mid, mid, lin, idxs, map, n, 0, 0, 1, use_map);
    sbb_conv_old<<<n / 4, 256, 0, stream>>>(
        feats, mid, w2, g2, b2, feats,
        out, (unsigned short*)out, lin, idxs, map, n, 1, 1, 0, use_map);
}